// Round 3
// baseline (460.721 us; speedup 1.0000x reference)
//
#include <hip/hip_runtime.h>
#include <hip/hip_cooperative_groups.h>
#include <stdint.h>
#include <stddef.h>

namespace cg = cooperative_groups;

#define B_ 4
#define T_ 8192
#define D_ 1024
#define NBLK 64
#define SEGL 128
#define TOPK_ 16
#define NS 21          // 16 micro + 4 macro + 1 glob
#define MPAD 96
#define RMS_EPS_ 1.1920929e-07f
#define PART 98304     // 96*1024, one partial-C slice

typedef float f32x4 __attribute__((ext_vector_type(4)));
typedef __bf16 bf16x8 __attribute__((ext_vector_type(8)));
typedef unsigned short us8 __attribute__((ext_vector_type(8)));

__device__ __forceinline__ unsigned short f2bf(float f) {
    union { float f; unsigned int u; } v; v.f = f;
    unsigned int r = v.u + 0x7FFFu + ((v.u >> 16) & 1u);
    return (unsigned short)(r >> 16);
}
__device__ __forceinline__ float4 ld4(const float* p) { return *(const float4*)p; }

// ---------------------------------------------------------------------------
// K1: per-(b,blk) segment mean, hid_score, sur_score. (unchanged from r2)
// ---------------------------------------------------------------------------
__global__ __launch_bounds__(1024) void seg_stats(
        const float* __restrict__ ph, const float* __restrict__ nll,
        float* __restrict__ seg_mean, float* __restrict__ hid, float* __restrict__ sur) {
    int g = blockIdx.x; int b = g >> 6; int blk = g & 63;
    int tid = threadIdx.x; int chunk = tid >> 8; int c = tid & 255;
    const float* base = ph + ((size_t)b * T_ + blk * SEGL + chunk * 32) * D_ + 4 * c;
    const float* p0 = base;
    const float* p1 = base + (size_t)8  * D_;
    const float* p2 = base + (size_t)16 * D_;
    const float* p3 = base + (size_t)24 * D_;
    f32x4 a0 = {0,0,0,0}, a1 = {0,0,0,0}, a2 = {0,0,0,0}, a3 = {0,0,0,0};
    #pragma unroll
    for (int r = 0; r < 8; r++) {
        float4 v0 = ld4(p0 + (size_t)r * D_);
        float4 v1 = ld4(p1 + (size_t)r * D_);
        float4 v2 = ld4(p2 + (size_t)r * D_);
        float4 v3 = ld4(p3 + (size_t)r * D_);
        a0.x += v0.x; a0.y += v0.y; a0.z += v0.z; a0.w += v0.w;
        a1.x += v1.x; a1.y += v1.y; a1.z += v1.z; a1.w += v1.w;
        a2.x += v2.x; a2.y += v2.y; a2.z += v2.z; a2.w += v2.w;
        a3.x += v3.x; a3.y += v3.y; a3.z += v3.z; a3.w += v3.w;
    }
    float sx = a0.x + a1.x + a2.x + a3.x;
    float sy = a0.y + a1.y + a2.y + a3.y;
    float sz = a0.z + a1.z + a2.z + a3.z;
    float sw = a0.w + a1.w + a2.w + a3.w;

    __shared__ float4 tmp[3][256];
    __shared__ float redw[4];
    __shared__ float surw;
    if (chunk) {
        float4 t; t.x = sx; t.y = sy; t.z = sz; t.w = sw;
        tmp[chunk - 1][c] = t;
        if (tid >= 256 && tid < 320) {
            int i = tid - 256;
            float v = nll[b * T_ + blk * SEGL + i] + nll[b * T_ + blk * SEGL + 64 + i];
            #pragma unroll
            for (int o = 32; o; o >>= 1) v += __shfl_xor(v, o);
            if (i == 0) surw = v * (1.f/128.f);
        }
    }
    __syncthreads();
    if (chunk == 0) {
        float4 t0 = tmp[0][c], t1 = tmp[1][c], t2 = tmp[2][c];
        float mx = (sx + t0.x + t1.x + t2.x) * (1.f/128.f);
        float my = (sy + t0.y + t1.y + t2.y) * (1.f/128.f);
        float mz = (sz + t0.z + t1.z + t2.z) * (1.f/128.f);
        float mw = (sw + t0.w + t1.w + t2.w) * (1.f/128.f);
        float4 m; m.x = mx; m.y = my; m.z = mz; m.w = mw;
        *(float4*)(seg_mean + (size_t)g * D_ + 4 * c) = m;
        float rv = mx*mx + my*my + mz*mz + mw*mw;
        #pragma unroll
        for (int o = 32; o; o >>= 1) rv += __shfl_xor(rv, o);
        if ((tid & 63) == 0) redw[tid >> 6] = rv;
    }
    __syncthreads();
    if (tid == 0) {
        hid[g] = sqrtf(redw[0] + redw[1] + redw[2] + redw[3]);
        sur[g] = surw;
    }
}

// ---------------------------------------------------------------------------
// gemm chunk (device fn): one 64-col n-strip x one 256-wide k-chunk of
// C[96x1024] = A[96xK] @ Bw[1024xK]^T, written to Cp (caller adds kc*PART).
// AMODE 0: A bf16 [96xK]. AMODE 1: A = 4 fp32 partial slices [96x1024]+p*PART.
// 512 threads; LDS Bs[64*264] + As[96*264] shorts from caller.
// ---------------------------------------------------------------------------
template<int K, int AMODE>
__device__ __forceinline__ void gemm_chunk(
        const void* __restrict__ Av, const float* __restrict__ Bw,
        float* __restrict__ Cp, int n0, int kc, int tid,
        unsigned short* Bs, unsigned short* As) {
    int wave = tid >> 6, lane = tid & 63;
    int quad = lane >> 4, l16 = lane & 15;
    int strip = wave >> 1, kh = wave & 1;

    // ---- stage B: rows n0..n0+63, cols kc*256..+256, fp32 -> bf16
    #pragma unroll
    for (int i = 0; i < 4; i++) {
        int id = tid + 512 * i;
        int r = id >> 5, c = id & 31;
        const float* src = Bw + (size_t)(n0 + r) * K + kc * 256 + c * 8;
        float4 v0 = ld4(src), v1 = ld4(src + 4);
        us8 h;
        h[0] = f2bf(v0.x); h[1] = f2bf(v0.y); h[2] = f2bf(v0.z); h[3] = f2bf(v0.w);
        h[4] = f2bf(v1.x); h[5] = f2bf(v1.y); h[6] = f2bf(v1.z); h[7] = f2bf(v1.w);
        *(us8*)&Bs[r * 264 + c * 8] = h;
    }
    // ---- stage A
    #pragma unroll
    for (int i = 0; i < 6; i++) {
        int id = tid + 512 * i;
        int r = id >> 5, c = id & 31;
        if (AMODE == 0) {
            const unsigned short* A = (const unsigned short*)Av;
            *(us8*)&As[r * 264 + c * 8] =
                *(const us8*)(A + (size_t)r * K + kc * 256 + c * 8);
        } else {
            const float* A = (const float*)Av;   // 4 partial slices, K==1024
            const float* s0 = A + (size_t)r * 1024 + kc * 256 + c * 8;
            float4 a0 = ld4(s0), a1 = ld4(s0 + 4);
            #pragma unroll
            for (int p = 1; p < 4; p++) {
                float4 b0 = ld4(s0 + p * PART), b1 = ld4(s0 + p * PART + 4);
                a0.x += b0.x; a0.y += b0.y; a0.z += b0.z; a0.w += b0.w;
                a1.x += b1.x; a1.y += b1.y; a1.z += b1.z; a1.w += b1.w;
            }
            us8 h;
            h[0] = f2bf(a0.x); h[1] = f2bf(a0.y); h[2] = f2bf(a0.z); h[3] = f2bf(a0.w);
            h[4] = f2bf(a1.x); h[5] = f2bf(a1.y); h[6] = f2bf(a1.z); h[7] = f2bf(a1.w);
            *(us8*)&As[r * 264 + c * 8] = h;
        }
    }
    __syncthreads();

    // ---- compute: wave = (strip, khalf); 6 M-tiles x 4 k-steps of 32
    f32x4 acc[6];
    #pragma unroll
    for (int i = 0; i < 6; i++) acc[i] = (f32x4){0.f, 0.f, 0.f, 0.f};
    const unsigned short* bbase = &Bs[(strip * 16 + l16) * 264 + kh * 128 + quad * 8];
    const unsigned short* abase = &As[l16 * 264 + kh * 128 + quad * 8];
    #pragma unroll
    for (int kk = 0; kk < 128; kk += 32) {
        bf16x8 bfr = __builtin_bit_cast(bf16x8, *(const us8*)(bbase + kk));
        #pragma unroll
        for (int mi = 0; mi < 6; mi++) {
            bf16x8 af = __builtin_bit_cast(bf16x8, *(const us8*)(abase + mi * 16 * 264 + kk));
            acc[mi] = __builtin_amdgcn_mfma_f32_16x16x32_bf16(af, bfr, acc[mi], 0, 0, 0);
        }
    }
    __syncthreads();                       // done reading As; reuse as scratch

    // ---- epilogue: kh-reduce in LDS (stride 68), cooperative f4 store.
    float* scr = (float*)As;               // 96*68*4 = 26112 B
    const int SS = 68;
    if (kh == 1) {
        #pragma unroll
        for (int mi = 0; mi < 6; mi++)
            #pragma unroll
            for (int r = 0; r < 4; r++)
                scr[(mi * 16 + quad * 4 + r) * SS + strip * 16 + l16] = acc[mi][r];
    }
    __syncthreads();
    if (kh == 0) {
        #pragma unroll
        for (int mi = 0; mi < 6; mi++)
            #pragma unroll
            for (int r = 0; r < 4; r++)
                scr[(mi * 16 + quad * 4 + r) * SS + strip * 16 + l16] += acc[mi][r];
    }
    __syncthreads();
    #pragma unroll
    for (int i = 0; i < 3; i++) {
        int id = tid + 512 * i;            // 96 rows * 16 float4
        int row = id >> 4, c4 = (id & 15) << 2;
        float4 v = *(const float4*)&scr[row * SS + c4];
        *(float4*)&Cp[(size_t)row * 1024 + n0 + c4] = v;
    }
}

// ---------------------------------------------------------------------------
// MEGA: cooperative fusion of feats -> gemm1 -> rmsnorm -> gemm2 -> gemm3 ->
// attn. 128 blocks x 512 threads, 5 grid syncs. Removes 5 kernel-launch
// boundaries + inter-kernel drain bubbles; intermediates stay L2-hot.
// ---------------------------------------------------------------------------
__global__ __launch_bounds__(512) void mega(
        const float* __restrict__ ph, const float* __restrict__ query,
        const float* __restrict__ W_sum, const float* __restrict__ W_k,
        const float* __restrict__ W_v, const float* __restrict__ W_o,
        const float* __restrict__ seg_mean, const float* __restrict__ hid,
        const float* __restrict__ sur,
        unsigned short* __restrict__ feats, float* __restrict__ presum_p,
        unsigned short* __restrict__ summ_b,
        float* __restrict__ keys_p, float* __restrict__ vals_p,
        float* __restrict__ valsO_p, float* __restrict__ out) {
    cg::grid_group grid = cg::this_grid();
    __shared__ __align__(16) unsigned short smem_us[160 * 264];  // 84480 B
    unsigned short* Bs = smem_us;
    unsigned short* As = smem_us + 64 * 264;
    int bid = blockIdx.x, tid = threadIdx.x;

    // ===== Phase A: feats assembly (blocks 0..95) =====
    if (bid < MPAD) {
        int r = bid, t = tid;
        if (r >= B_ * NS) {
            if (t < 256) {
                ushort4 z4; z4.x = z4.y = z4.z = z4.w = 0;
                unsigned short* row0 = feats + (size_t)r * 2048 + 4 * t;
                *(ushort4*)row0 = z4; *(ushort4*)(row0 + 1024) = z4;
            }
        } else {
            int b = r / NS, s = r % NS;
            float* sc = (float*)smem_us;           // 64 floats
            int* sidx = (int*)(smem_us + 128);     // 16 ints at byte 256
            if (t < 64) {
                float h = hid[b * NBLK + t];
                float ss0 = sur[b * NBLK + t];
                float mh = h; for (int o = 32; o; o >>= 1) mh += __shfl_xor(mh, o); mh *= (1.f/64.f);
                float dh = h - mh; float vh = dh * dh;
                for (int o = 32; o; o >>= 1) vh += __shfl_xor(vh, o); vh *= (1.f/64.f);
                float sh = fmaxf(sqrtf(vh), 1e-6f);
                float ms = ss0; for (int o = 32; o; o >>= 1) ms += __shfl_xor(ms, o); ms *= (1.f/64.f);
                float ds = ss0 - ms; float vs = ds * ds;
                for (int o = 32; o; o >>= 1) vs += __shfl_xor(vs, o); vs *= (1.f/64.f);
                float ssd = fmaxf(sqrtf(vs), 1e-6f);
                sc[t] = dh / sh + ds / ssd;
            }
            __syncthreads();
            if (t < 64) {
                float z = sc[t];
                int rank = 0;
                for (int j = 0; j < 64; j++) {
                    float oj = sc[j];
                    rank += (oj > z) || (oj == z && j < t);
                }
                bool sel = rank < TOPK_;
                unsigned long long mask = __ballot(sel);
                int pos = __popcll(mask & ((1ull << t) - 1ull));
                if (sel) sidx[pos] = t;
            }
            __syncthreads();
            if (t < 256) {
                float mx = 0, my = 0, mz = 0, mw = 0;
                int lastrow;
                if (s < 16) {
                    int blk = sidx[s];
                    float4 v = ld4(seg_mean + (size_t)(b * NBLK + blk) * D_ + 4 * t);
                    mx = v.x; my = v.y; mz = v.z; mw = v.w;
                    lastrow = blk * SEGL + SEGL - 1;
                } else if (s < 20) {
                    int m = s - 16;
                    for (int j = 0; j < 16; j++) {
                        float4 v = ld4(seg_mean + (size_t)(b * NBLK + m * 16 + j) * D_ + 4 * t);
                        mx += v.x; my += v.y; mz += v.z; mw += v.w;
                    }
                    mx *= (1.f/16.f); my *= (1.f/16.f); mz *= (1.f/16.f); mw *= (1.f/16.f);
                    lastrow = m * 2048 + 2047;
                } else {
                    for (int j = 0; j < 64; j++) {
                        float4 v = ld4(seg_mean + (size_t)(b * NBLK + j) * D_ + 4 * t);
                        mx += v.x; my += v.y; mz += v.z; mw += v.w;
                    }
                    mx *= (1.f/64.f); my *= (1.f/64.f); mz *= (1.f/64.f); mw *= (1.f/64.f);
                    lastrow = T_ - 1;
                }
                float4 lv = ld4(ph + ((size_t)b * T_ + lastrow) * D_ + 4 * t);
                ushort4 hm; hm.x = f2bf(mx); hm.y = f2bf(my); hm.z = f2bf(mz); hm.w = f2bf(mw);
                ushort4 hl; hl.x = f2bf(lv.x); hl.y = f2bf(lv.y); hl.z = f2bf(lv.z); hl.w = f2bf(lv.w);
                unsigned short* row0 = feats + (size_t)r * 2048 + 4 * t;
                *(ushort4*)row0 = hm;
                *(ushort4*)(row0 + 1024) = hl;
            }
        }
    }
    __threadfence(); grid.sync();

    // ===== Phase B: gemm1 split-K: presum_p[kc] = feats @ W_sum^T (128 blk) =====
    {
        int strip = bid >> 3, kc = bid & 7;
        gemm_chunk<2048, 0>(feats, W_sum, presum_p + (size_t)kc * PART,
                            strip * 64, kc, tid, Bs, As);
    }
    __threadfence(); grid.sync();

    // ===== Phase C: rmsnorm over 8 partial slices (blocks 0..95) =====
    if (bid < MPAD) {
        int r = bid, t = tid;
        float* red = (float*)smem_us;
        float4 v = (float4){0.f, 0.f, 0.f, 0.f};
        if (t < 256) {
            #pragma unroll
            for (int c = 0; c < 8; c++) {
                float4 u = ld4(presum_p + (size_t)c * PART + (size_t)r * D_ + 4 * t);
                v.x += u.x; v.y += u.y; v.z += u.z; v.w += u.w;
            }
            red[t] = v.x*v.x + v.y*v.y + v.z*v.z + v.w*v.w;
        }
        __syncthreads();
        for (int s2 = 128; s2 > 0; s2 >>= 1) { if (t < s2) red[t] += red[t + s2]; __syncthreads(); }
        float scale = rsqrtf(red[0] * (1.f/1024.f) + RMS_EPS_);
        if (t < 256) {
            ushort4 h;
            h.x = f2bf(v.x * scale); h.y = f2bf(v.y * scale);
            h.z = f2bf(v.z * scale); h.w = f2bf(v.w * scale);
            *(ushort4*)(summ_b + (size_t)r * D_ + 4 * t) = h;
        }
    }
    __threadfence(); grid.sync();

    // ===== Phase D: gemm2 split-K: keys_p / vals_p (exactly 128 blocks) =====
    {
        int mat = bid >> 6, inner = bid & 63;
        int strip = inner >> 2, kc = inner & 3;
        gemm_chunk<1024, 0>(summ_b, mat ? W_v : W_k,
                            (mat ? vals_p : keys_p) + (size_t)kc * PART,
                            strip * 64, kc, tid, Bs, As);
    }
    __threadfence(); grid.sync();

    // ===== Phase E: gemm3: valsO_p = (sum vals_p slices) @ W_o^T (64 blocks) =====
    if (bid < 64) {
        int strip = bid >> 2, kc = bid & 3;
        gemm_chunk<1024, 1>(vals_p, W_o, valsO_p + (size_t)kc * PART,
                            strip * 64, kc, tid, Bs, As);
    }
    __threadfence(); grid.sync();

    // ===== Phase F: attention (2 (b,q) pairs per block) =====
    {
        int h = tid >> 8;                 // half: 0 or 1
        int p = bid * 2 + h;              // pair 0..255
        int t8 = tid & 255;
        int b = p >> 6, q = p & 63;
        int wave4 = t8 >> 6, lane = t8 & 63;
        float* attnw = (float*)smem_us;   // [2][24]
        float* aw = attnw + h * 24;
        const float* qrow = query + (size_t)q * D_ + lane * 16;
        float4 qv0 = ld4(qrow), qv1 = ld4(qrow + 4), qv2 = ld4(qrow + 8), qv3 = ld4(qrow + 12);
        for (int s = wave4; s < NS; s += 4) {
            const float* krow = keys_p + (size_t)(b * NS + s) * D_ + lane * 16;
            float4 k0 = (float4){0,0,0,0}, k1 = k0, k2 = k0, k3 = k0;
            #pragma unroll
            for (int c = 0; c < 4; c++) {
                const float* kp = krow + (size_t)c * PART;
                float4 u0 = ld4(kp), u1 = ld4(kp + 4), u2 = ld4(kp + 8), u3 = ld4(kp + 12);
                k0.x += u0.x; k0.y += u0.y; k0.z += u0.z; k0.w += u0.w;
                k1.x += u1.x; k1.y += u1.y; k1.z += u1.z; k1.w += u1.w;
                k2.x += u2.x; k2.y += u2.y; k2.z += u2.z; k2.w += u2.w;
                k3.x += u3.x; k3.y += u3.y; k3.z += u3.z; k3.w += u3.w;
            }
            float a = qv0.x*k0.x + qv0.y*k0.y + qv0.z*k0.z + qv0.w*k0.w
                    + qv1.x*k1.x + qv1.y*k1.y + qv1.z*k1.z + qv1.w*k1.w
                    + qv2.x*k2.x + qv2.y*k2.y + qv2.z*k2.z + qv2.w*k2.w
                    + qv3.x*k3.x + qv3.y*k3.y + qv3.z*k3.z + qv3.w*k3.w;
            for (int o = 32; o; o >>= 1) a += __shfl_xor(a, o);
            if (lane == 0) aw[s] = a * 0.03125f;   // /sqrt(1024)
        }
        __syncthreads();
        if (t8 < 32) {                    // wave-parallel softmax over NS=21
            float v = (t8 < NS) ? aw[t8] : -3.0e38f;
            float m = v;
            #pragma unroll
            for (int o = 16; o; o >>= 1) m = fmaxf(m, __shfl_xor(m, o));
            float e = (t8 < NS) ? expf(v - m) : 0.f;
            float s2 = e;
            #pragma unroll
            for (int o = 16; o; o >>= 1) s2 += __shfl_xor(s2, o);
            if (t8 < NS) aw[t8] = e / s2;
        }
        __syncthreads();
        float ax = 0, ay = 0, az = 0, aw4 = 0;
        #pragma unroll
        for (int s = 0; s < NS; s++) {
            float w = aw[s];
            float4 v = (float4){0,0,0,0};
            #pragma unroll
            for (int c = 0; c < 4; c++) {
                float4 u = ld4(valsO_p + (size_t)c * PART + (size_t)(b * NS + s) * D_ + 4 * t8);
                v.x += u.x; v.y += u.y; v.z += u.z; v.w += u.w;
            }
            ax += w * v.x; ay += w * v.y; az += w * v.z; aw4 += w * v.w;
        }
        float4 o4; o4.x = ax; o4.y = ay; o4.z = az; o4.w = aw4;
        *(float4*)(out + (size_t)p * D_ + 4 * t8) = o4;
    }
}

// ---------------------------------------------------------------------------
extern "C" void kernel_launch(void* const* d_in, const int* in_sizes, int n_in,
                              void* d_out, int out_size, void* d_ws, size_t ws_size,
                              hipStream_t stream) {
    (void)in_sizes; (void)n_in; (void)out_size; (void)ws_size;
    const float* ph    = (const float*)d_in[0];
    const float* nll   = (const float*)d_in[1];
    const float* query = (const float*)d_in[2];
    const float* W_sum = (const float*)d_in[3];
    const float* W_k   = (const float*)d_in[4];
    const float* W_v   = (const float*)d_in[5];
    const float* W_o   = (const float*)d_in[6];
    float* out = (float*)d_out;

    char* ws = (char*)d_ws;
    float*          seg_mean = (float*)(ws + 0);                 // 1048576 B
    float*          hid      = (float*)(ws + 1048576);           // 1024 B
    float*          sur      = (float*)(ws + 1049600);           // 1024 B
    unsigned short* feats    = (unsigned short*)(ws + 1050624);  // 393216 B
    float*          presum_p = (float*)(ws + 1443840);           // 8*384KB
    unsigned short* summ_b   = (unsigned short*)(ws + 4589568);  // 196608 B
    float*          keys_p   = (float*)(ws + 4786176);           // 4*384KB
    float*          vals_p   = (float*)(ws + 6359040);           // 4*384KB
    float*          valsO_p  = (float*)(ws + 7931904);           // 4*384KB

    seg_stats<<<B_ * NBLK, 1024, 0, stream>>>(ph, nll, seg_mean, hid, sur);

    void* args[] = {
        (void*)&ph, (void*)&query, (void*)&W_sum, (void*)&W_k, (void*)&W_v,
        (void*)&W_o, (void*)&seg_mean, (void*)&hid, (void*)&sur,
        (void*)&feats, (void*)&presum_p, (void*)&summ_b,
        (void*)&keys_p, (void*)&vals_p, (void*)&valsO_p, (void*)&out };
    hipLaunchCooperativeKernel((void*)mega, dim3(128), dim3(512), args, 0, stream);
}

// Round 5
// 248.273 us; speedup vs baseline: 1.8557x; 1.8557x over previous
//
#include <hip/hip_runtime.h>
#include <stdint.h>
#include <stddef.h>

#define B_ 4
#define T_ 8192
#define D_ 1024
#define NBLK 64
#define SEGL 128
#define TOPK_ 16
#define NS 21          // 16 micro + 4 macro + 1 glob
#define MPAD 96
#define RMS_EPS_ 1.1920929e-07f
#define PART 98304     // 96*1024, one partial-C slice

typedef float f32x4 __attribute__((ext_vector_type(4)));
typedef __bf16 bf16x8 __attribute__((ext_vector_type(8)));
typedef unsigned short us8 __attribute__((ext_vector_type(8)));

__device__ __forceinline__ unsigned short f2bf(float f) {
    union { float f; unsigned int u; } v; v.f = f;
    unsigned int r = v.u + 0x7FFFu + ((v.u >> 16) & 1u);
    return (unsigned short)(r >> 16);
}
__device__ __forceinline__ float4 ld4(const float* p) { return *(const float4*)p; }

// ---------------------------------------------------------------------------
// K1: per-(b,blk) segment mean, hid_score, sur_score. (r2 version — proven)
// 256 blocks x 1024 thr; 32 fully-unrolled independent float4 streams.
// ---------------------------------------------------------------------------
__global__ __launch_bounds__(1024) void seg_stats(
        const float* __restrict__ ph, const float* __restrict__ nll,
        float* __restrict__ seg_mean, float* __restrict__ hid, float* __restrict__ sur) {
    int g = blockIdx.x; int b = g >> 6; int blk = g & 63;
    int tid = threadIdx.x; int chunk = tid >> 8; int c = tid & 255;
    const float* base = ph + ((size_t)b * T_ + blk * SEGL + chunk * 32) * D_ + 4 * c;
    const float* p0 = base;
    const float* p1 = base + (size_t)8  * D_;
    const float* p2 = base + (size_t)16 * D_;
    const float* p3 = base + (size_t)24 * D_;
    f32x4 a0 = {0,0,0,0}, a1 = {0,0,0,0}, a2 = {0,0,0,0}, a3 = {0,0,0,0};
    #pragma unroll
    for (int r = 0; r < 8; r++) {
        float4 v0 = ld4(p0 + (size_t)r * D_);
        float4 v1 = ld4(p1 + (size_t)r * D_);
        float4 v2 = ld4(p2 + (size_t)r * D_);
        float4 v3 = ld4(p3 + (size_t)r * D_);
        a0.x += v0.x; a0.y += v0.y; a0.z += v0.z; a0.w += v0.w;
        a1.x += v1.x; a1.y += v1.y; a1.z += v1.z; a1.w += v1.w;
        a2.x += v2.x; a2.y += v2.y; a2.z += v2.z; a2.w += v2.w;
        a3.x += v3.x; a3.y += v3.y; a3.z += v3.z; a3.w += v3.w;
    }
    float sx = a0.x + a1.x + a2.x + a3.x;
    float sy = a0.y + a1.y + a2.y + a3.y;
    float sz = a0.z + a1.z + a2.z + a3.z;
    float sw = a0.w + a1.w + a2.w + a3.w;

    __shared__ float4 tmp[3][256];
    __shared__ float redw[4];
    __shared__ float surw;
    if (chunk) {
        float4 t; t.x = sx; t.y = sy; t.z = sz; t.w = sw;
        tmp[chunk - 1][c] = t;
        if (tid >= 256 && tid < 320) {
            int i = tid - 256;
            float v = nll[b * T_ + blk * SEGL + i] + nll[b * T_ + blk * SEGL + 64 + i];
            #pragma unroll
            for (int o = 32; o; o >>= 1) v += __shfl_xor(v, o);
            if (i == 0) surw = v * (1.f/128.f);
        }
    }
    __syncthreads();
    if (chunk == 0) {
        float4 t0 = tmp[0][c], t1 = tmp[1][c], t2 = tmp[2][c];
        float mx = (sx + t0.x + t1.x + t2.x) * (1.f/128.f);
        float my = (sy + t0.y + t1.y + t2.y) * (1.f/128.f);
        float mz = (sz + t0.z + t1.z + t2.z) * (1.f/128.f);
        float mw = (sw + t0.w + t1.w + t2.w) * (1.f/128.f);
        float4 m; m.x = mx; m.y = my; m.z = mz; m.w = mw;
        *(float4*)(seg_mean + (size_t)g * D_ + 4 * c) = m;
        float rv = mx*mx + my*my + mz*mz + mw*mw;
        #pragma unroll
        for (int o = 32; o; o >>= 1) rv += __shfl_xor(rv, o);
        if ((tid & 63) == 0) redw[tid >> 6] = rv;
    }
    __syncthreads();
    if (tid == 0) {
        hid[g] = sqrtf(redw[0] + redw[1] + redw[2] + redw[3]);
        sur[g] = surw;
    }
}

// ---------------------------------------------------------------------------
// K2: fused top-k + feats assembly (MPAD x 2048) bf16. (unchanged — proven)
// ---------------------------------------------------------------------------
__global__ __launch_bounds__(256) void feats_build(
        const float* __restrict__ ph, const float* __restrict__ seg_mean,
        const float* __restrict__ hid, const float* __restrict__ sur,
        unsigned short* __restrict__ feats) {
    int r = blockIdx.x; int t = threadIdx.x;
    unsigned short* row0 = feats + (size_t)r * 2048 + 4 * t;
    unsigned short* row1 = row0 + 1024;
    if (r >= B_ * NS) {
        ushort4 z4; z4.x = z4.y = z4.z = z4.w = 0;
        *(ushort4*)row0 = z4; *(ushort4*)row1 = z4;
        return;
    }
    int b = r / NS, s = r % NS;
    __shared__ float sc[64];
    __shared__ int sidx[16];
    if (t < 64) {
        float h = hid[b * NBLK + t];
        float ss0 = sur[b * NBLK + t];
        float mh = h; for (int o = 32; o; o >>= 1) mh += __shfl_xor(mh, o); mh *= (1.f/64.f);
        float dh = h - mh; float vh = dh * dh;
        for (int o = 32; o; o >>= 1) vh += __shfl_xor(vh, o); vh *= (1.f/64.f);
        float sh = fmaxf(sqrtf(vh), 1e-6f);
        float ms = ss0; for (int o = 32; o; o >>= 1) ms += __shfl_xor(ms, o); ms *= (1.f/64.f);
        float ds = ss0 - ms; float vs = ds * ds;
        for (int o = 32; o; o >>= 1) vs += __shfl_xor(vs, o); vs *= (1.f/64.f);
        float ssd = fmaxf(sqrtf(vs), 1e-6f);
        sc[t] = dh / sh + ds / ssd;
    }
    __syncthreads();
    if (t < 64) {
        float z = sc[t];
        int rank = 0;
        for (int j = 0; j < 64; j++) {
            float oj = sc[j];
            rank += (oj > z) || (oj == z && j < t);
        }
        bool sel = rank < TOPK_;
        unsigned long long mask = __ballot(sel);
        int pos = __popcll(mask & ((1ull << t) - 1ull));
        if (sel) sidx[pos] = t;
    }
    __syncthreads();

    float mx = 0, my = 0, mz = 0, mw = 0;
    int lastrow;
    if (s < 16) {
        int blk = sidx[s];
        float4 v = ld4(seg_mean + (size_t)(b * NBLK + blk) * D_ + 4 * t);
        mx = v.x; my = v.y; mz = v.z; mw = v.w;
        lastrow = blk * SEGL + SEGL - 1;
    } else if (s < 20) {
        int m = s - 16;
        for (int j = 0; j < 16; j++) {
            float4 v = ld4(seg_mean + (size_t)(b * NBLK + m * 16 + j) * D_ + 4 * t);
            mx += v.x; my += v.y; mz += v.z; mw += v.w;
        }
        mx *= (1.f/16.f); my *= (1.f/16.f); mz *= (1.f/16.f); mw *= (1.f/16.f);
        lastrow = m * 2048 + 2047;
    } else {
        for (int j = 0; j < 64; j++) {
            float4 v = ld4(seg_mean + (size_t)(b * NBLK + j) * D_ + 4 * t);
            mx += v.x; my += v.y; mz += v.z; mw += v.w;
        }
        mx *= (1.f/64.f); my *= (1.f/64.f); mz *= (1.f/64.f); mw *= (1.f/64.f);
        lastrow = T_ - 1;
    }
    float4 lv = ld4(ph + ((size_t)b * T_ + lastrow) * D_ + 4 * t);
    ushort4 hm; hm.x = f2bf(mx); hm.y = f2bf(my); hm.z = f2bf(mz); hm.w = f2bf(mw);
    ushort4 hl; hl.x = f2bf(lv.x); hl.y = f2bf(lv.y); hl.z = f2bf(lv.z); hl.w = f2bf(lv.w);
    *(ushort4*)row0 = hm;
    *(ushort4*)row1 = hl;
}

// ---------------------------------------------------------------------------
// K4: split-K LDS-staged MFMA GEMM (r0 structure — fastest measured — with
// r2's vectorized epilogue). C[96x1024] = A[96xK] @ Bw[1024xK]^T, block =
// (n-strip x, k-chunk y), writes partial slice at Cp + kc*PART.
// AMODE 0: A bf16 [96xK]. AMODE 1: A = 4 fp32 partial slices (K==1024).
// DO_RED: blocks with y==4 instead reduce 4 slices of R4 -> Rf (rides the
// gemm3 dispatch for free: keys-final doesn't depend on gemm3's work).
// ---------------------------------------------------------------------------
template<int K, int AMODE, int DO_RED>
__global__ __launch_bounds__(512) void gemm_lds(
        const void* __restrict__ Av,
        const float* __restrict__ B0, const float* __restrict__ B1,
        float* __restrict__ C0, float* __restrict__ C1,
        const float* __restrict__ R4, float* __restrict__ Rf) {
    if (DO_RED && blockIdx.y == 4) {
        // 16 blocks x 512 thr: Rf[96x1024] = sum of 4 slices of R4
        int bx = blockIdx.x, t = threadIdx.x;
        #pragma unroll
        for (int i = 0; i < 3; i++) {
            int id = t + 512 * i;              // 0..1535 = 6 rows * 256 f4
            int rl = id >> 8, c4 = (id & 255) << 2;
            size_t off = (size_t)(bx * 6 + rl) * 1024 + c4;
            float4 a = ld4(R4 + off);
            float4 b = ld4(R4 + off + PART);
            float4 c = ld4(R4 + off + 2 * (size_t)PART);
            float4 d = ld4(R4 + off + 3 * (size_t)PART);
            a.x += b.x + c.x + d.x; a.y += b.y + c.y + d.y;
            a.z += b.z + c.z + d.z; a.w += b.w + c.w + d.w;
            *(float4*)(Rf + off) = a;
        }
        return;
    }
    const float* Bw = blockIdx.z ? B1 : B0;
    float* Cp       = blockIdx.z ? C1 : C0;
    int n0 = blockIdx.x * 64;
    int kc = blockIdx.y;
    Cp += (size_t)kc * PART;
    int tid = threadIdx.x, wave = tid >> 6, lane = tid & 63;
    int quad = lane >> 4, l16 = lane & 15;

    __shared__ __align__(16) unsigned short Bs[64 * 264];   // 33792 B
    __shared__ __align__(16) unsigned short As[96 * 264];   // 50688 B

    // ---- stage B: rows n0..n0+63, cols kc*256..+256, fp32 -> bf16
    #pragma unroll
    for (int i = 0; i < 4; i++) {
        int id = tid + 512 * i;
        int r = id >> 5, c = id & 31;
        const float* src = Bw + (size_t)(n0 + r) * K + kc * 256 + c * 8;
        float4 v0 = ld4(src), v1 = ld4(src + 4);
        us8 h;
        h[0] = f2bf(v0.x); h[1] = f2bf(v0.y); h[2] = f2bf(v0.z); h[3] = f2bf(v0.w);
        h[4] = f2bf(v1.x); h[5] = f2bf(v1.y); h[6] = f2bf(v1.z); h[7] = f2bf(v1.w);
        *(us8*)&Bs[r * 264 + c * 8] = h;
    }
    // ---- stage A
    #pragma unroll
    for (int i = 0; i < 6; i++) {
        int id = tid + 512 * i;
        int r = id >> 5, c = id & 31;
        if (AMODE == 0) {
            const unsigned short* A = (const unsigned short*)Av;
            *(us8*)&As[r * 264 + c * 8] =
                *(const us8*)(A + (size_t)r * K + kc * 256 + c * 8);
        } else {
            const float* A = (const float*)Av;   // 4 partial slices, K==1024
            const float* s0 = A + (size_t)r * 1024 + kc * 256 + c * 8;
            float4 a0 = ld4(s0), a1 = ld4(s0 + 4);
            #pragma unroll
            for (int p = 1; p < 4; p++) {
                float4 b0 = ld4(s0 + p * PART), b1 = ld4(s0 + p * PART + 4);
                a0.x += b0.x; a0.y += b0.y; a0.z += b0.z; a0.w += b0.w;
                a1.x += b1.x; a1.y += b1.y; a1.z += b1.z; a1.w += b1.w;
            }
            us8 h;
            h[0] = f2bf(a0.x); h[1] = f2bf(a0.y); h[2] = f2bf(a0.z); h[3] = f2bf(a0.w);
            h[4] = f2bf(a1.x); h[5] = f2bf(a1.y); h[6] = f2bf(a1.z); h[7] = f2bf(a1.w);
            *(us8*)&As[r * 264 + c * 8] = h;
        }
    }
    __syncthreads();

    // ---- compute: wave = (strip, khalf); 6 M-tiles x 4 k-steps of 32
    int strip = wave >> 1, kh = wave & 1;
    f32x4 acc[6];
    #pragma unroll
    for (int i = 0; i < 6; i++) acc[i] = (f32x4){0.f, 0.f, 0.f, 0.f};
    const unsigned short* bbase = &Bs[(strip * 16 + l16) * 264 + kh * 128 + quad * 8];
    const unsigned short* abase = &As[l16 * 264 + kh * 128 + quad * 8];
    #pragma unroll
    for (int kk = 0; kk < 128; kk += 32) {
        bf16x8 bfr = __builtin_bit_cast(bf16x8, *(const us8*)(bbase + kk));
        #pragma unroll
        for (int mi = 0; mi < 6; mi++) {
            bf16x8 af = __builtin_bit_cast(bf16x8, *(const us8*)(abase + mi * 16 * 264 + kk));
            acc[mi] = __builtin_amdgcn_mfma_f32_16x16x32_bf16(af, bfr, acc[mi], 0, 0, 0);
        }
    }
    __syncthreads();                       // done reading As; reuse as scratch

    // ---- epilogue: kh-reduce in LDS (stride 68), cooperative f4 store.
    float* scr = (float*)As;               // 96*68*4 = 26112 B
    const int SS = 68;
    if (kh == 1) {
        #pragma unroll
        for (int mi = 0; mi < 6; mi++)
            #pragma unroll
            for (int r = 0; r < 4; r++)
                scr[(mi * 16 + quad * 4 + r) * SS + strip * 16 + l16] = acc[mi][r];
    }
    __syncthreads();
    if (kh == 0) {
        #pragma unroll
        for (int mi = 0; mi < 6; mi++)
            #pragma unroll
            for (int r = 0; r < 4; r++)
                scr[(mi * 16 + quad * 4 + r) * SS + strip * 16 + l16] += acc[mi][r];
    }
    __syncthreads();
    #pragma unroll
    for (int i = 0; i < 3; i++) {
        int id = tid + 512 * i;            // 96 rows * 16 float4
        int row = id >> 4, c4 = (id & 15) << 2;
        float4 v = *(const float4*)&scr[row * SS + c4];
        *(float4*)&Cp[(size_t)row * 1024 + n0 + c4] = v;
    }
}

// ---------------------------------------------------------------------------
// K5: sum 8 presum partials, RMSNorm, emit bf16 summaries. grid 96 x 256.
// ---------------------------------------------------------------------------
__global__ __launch_bounds__(256) void rmsnorm8(
        const float* __restrict__ pp, unsigned short* __restrict__ y) {
    int r = blockIdx.x; int t = threadIdx.x;
    float4 v = (float4){0.f, 0.f, 0.f, 0.f};
    #pragma unroll
    for (int c = 0; c < 8; c++) {
        float4 u = ld4(pp + (size_t)c * PART + (size_t)r * D_ + 4 * t);
        v.x += u.x; v.y += u.y; v.z += u.z; v.w += u.w;
    }
    __shared__ float red[256];
    red[t] = v.x*v.x + v.y*v.y + v.z*v.z + v.w*v.w;
    __syncthreads();
    for (int s2 = 128; s2 > 0; s2 >>= 1) { if (t < s2) red[t] += red[t + s2]; __syncthreads(); }
    float scale = rsqrtf(red[0] * (1.f/1024.f) + RMS_EPS_);
    ushort4 h;
    h.x = f2bf(v.x * scale); h.y = f2bf(v.y * scale);
    h.z = f2bf(v.z * scale); h.w = f2bf(v.w * scale);
    *(ushort4*)(y + (size_t)r * D_ + 4 * t) = h;
}

// ---------------------------------------------------------------------------
// K6: logits/softmax/mix. keys arrives FINAL (reduced in gemm3's dispatch);
// valsO arrives as 4 fp32 partial slices. grid 256 (b*64+q), block 256.
// ---------------------------------------------------------------------------
__global__ __launch_bounds__(256) void attn_out(
        const float* __restrict__ query, const float* __restrict__ keys,
        const float* __restrict__ valsO_p, float* __restrict__ out) {
    int g = blockIdx.x; int b = g >> 6; int q = g & 63;
    int tid = threadIdx.x, wave = tid >> 6, lane = tid & 63;
    __shared__ float attnw[24];
    const float* qrow = query + (size_t)q * D_ + lane * 16;
    float4 qv0 = ld4(qrow), qv1 = ld4(qrow + 4), qv2 = ld4(qrow + 8), qv3 = ld4(qrow + 12);
    for (int s = wave; s < NS; s += 4) {
        const float* kp = keys + (size_t)(b * NS + s) * D_ + lane * 16;
        float4 u0 = ld4(kp), u1 = ld4(kp + 4), u2 = ld4(kp + 8), u3 = ld4(kp + 12);
        float a = qv0.x*u0.x + qv0.y*u0.y + qv0.z*u0.z + qv0.w*u0.w
                + qv1.x*u1.x + qv1.y*u1.y + qv1.z*u1.z + qv1.w*u1.w
                + qv2.x*u2.x + qv2.y*u2.y + qv2.z*u2.z + qv2.w*u2.w
                + qv3.x*u3.x + qv3.y*u3.y + qv3.z*u3.z + qv3.w*u3.w;
        for (int o = 32; o; o >>= 1) a += __shfl_xor(a, o);
        if (lane == 0) attnw[s] = a * 0.03125f;   // /sqrt(1024)
    }
    __syncthreads();
    if (tid < 32) {                        // wave-parallel softmax over NS=21
        float v = (tid < NS) ? attnw[tid] : -3.0e38f;
        float m = v;
        #pragma unroll
        for (int o = 16; o; o >>= 1) m = fmaxf(m, __shfl_xor(m, o));
        float e = (tid < NS) ? expf(v - m) : 0.f;
        float s2 = e;
        #pragma unroll
        for (int o = 16; o; o >>= 1) s2 += __shfl_xor(s2, o);
        if (tid < NS) attnw[tid] = e / s2;
    }
    __syncthreads();
    float ax = 0, ay = 0, az = 0, aw = 0;
    #pragma unroll
    for (int s = 0; s < NS; s++) {
        float w = attnw[s];
        float4 v = (float4){0,0,0,0};
        #pragma unroll
        for (int c = 0; c < 4; c++) {
            float4 u = ld4(valsO_p + (size_t)c * PART + (size_t)(b * NS + s) * D_ + 4 * tid);
            v.x += u.x; v.y += u.y; v.z += u.z; v.w += u.w;
        }
        ax += w * v.x; ay += w * v.y; az += w * v.z; aw += w * v.w;
    }
    float4 o4; o4.x = ax; o4.y = ay; o4.z = az; o4.w = aw;
    *(float4*)(out + (size_t)g * D_ + 4 * tid) = o4;
}

// ---------------------------------------------------------------------------
extern "C" void kernel_launch(void* const* d_in, const int* in_sizes, int n_in,
                              void* d_out, int out_size, void* d_ws, size_t ws_size,
                              hipStream_t stream) {
    (void)in_sizes; (void)n_in; (void)out_size; (void)ws_size;
    const float* ph    = (const float*)d_in[0];
    const float* nll   = (const float*)d_in[1];
    const float* query = (const float*)d_in[2];
    const float* W_sum = (const float*)d_in[3];
    const float* W_k   = (const float*)d_in[4];
    const float* W_v   = (const float*)d_in[5];
    const float* W_o   = (const float*)d_in[6];
    float* out = (float*)d_out;

    char* ws = (char*)d_ws;
    float*          seg_mean = (float*)(ws + 0);                 // 1048576 B
    float*          hid      = (float*)(ws + 1048576);           // 1024 B
    float*          sur      = (float*)(ws + 1049600);           // 1024 B
    unsigned short* feats    = (unsigned short*)(ws + 1050624);  // 393216 B
    float*          presum_p = (float*)(ws + 1443840);           // 8*384KB
    unsigned short* summ_b   = (unsigned short*)(ws + 4589568);  // 196608 B
    float*          keys_p   = (float*)(ws + 4786176);           // 4*384KB
    float*          vals_p   = (float*)(ws + 6359040);           // 4*384KB
    float*          valsO_p  = (float*)(ws + 7931904);           // 4*384KB
    float*          keys_f   = (float*)(ws + 9504768);           // 393216 B

    seg_stats<<<B_ * NBLK, 1024, 0, stream>>>(ph, nll, seg_mean, hid, sur);
    feats_build<<<MPAD, 256, 0, stream>>>(ph, seg_mean, hid, sur, feats);
    gemm_lds<2048, 0, 0><<<dim3(16, 8, 1), 512, 0, stream>>>(
        feats, W_sum, nullptr, presum_p, nullptr, nullptr, nullptr);
    rmsnorm8<<<MPAD, 256, 0, stream>>>(presum_p, summ_b);
    gemm_lds<1024, 0, 0><<<dim3(16, 4, 2), 512, 0, stream>>>(
        summ_b, W_k, W_v, keys_p, vals_p, nullptr, nullptr);
    gemm_lds<1024, 1, 1><<<dim3(16, 5, 1), 512, 0, stream>>>(
        vals_p, W_o, nullptr, valsO_p, nullptr, keys_p, keys_f);
    attn_out<<<B_ * NBLK, 256, 0, stream>>>(query, keys_f, valsO_p, out);
}